// Round 1
// baseline (157.240 us; speedup 1.0000x reference)
//
#include <hip/hip_runtime.h>
#include <hip/hip_fp16.h>

#define PP 7
#define SR 2
#define HH 128
#define WW 128
#define CC 256

__global__ __launch_bounds__(256) void roi_pool_kernel(
    const float* __restrict__ fm, const float* __restrict__ rois,
    float* __restrict__ out, int N) {
  const int roi = blockIdx.x;
  const int t = threadIdx.x;

  __shared__ float WX[WW], WY[HH];
  __shared__ int rowIdx[HH];
  __shared__ float rowW[HH];
  __shared__ int nrowsS, xloS, xhiS;

  if (t < 128) { WX[t] = 0.f; WY[t] = 0.f; }
  __syncthreads();

  // ---- geometry (redundant per-thread, cheap) ----
  const float bf  = rois[roi * 6 + 0];
  const float cx  = rois[roi * 6 + 2];
  const float cy  = rois[roi * 6 + 3];
  const float w_  = rois[roi * 6 + 4];
  const float h_  = rois[roi * 6 + 5];
  const int   b   = (int)bf;

  // f16 round-trip, contraction-free (match jnp float16 cast semantics)
  const float x1 = __half2float(__float2half(
      __fmul_rn(__fsub_rn(cx, __fmul_rn(0.5f, w_)), (float)HH)));
  const float y1 = __half2float(__float2half(
      __fmul_rn(__fsub_rn(cy, __fmul_rn(0.5f, h_)), (float)WW)));
  const float x2 = __half2float(__float2half(
      __fmul_rn(__fadd_rn(cx, __fmul_rn(0.5f, w_)), (float)HH)));
  const float y2 = __half2float(__float2half(
      __fmul_rn(__fadd_rn(cy, __fmul_rn(0.5f, h_)), (float)WW)));

  const float roi_w = fmaxf(__fsub_rn(x2, x1), 1.0f);
  const float roi_h = fmaxf(__fsub_rn(y2, y1), 1.0f);
  const float sx = roi_w / 7.0f;
  const float sy = roi_h / 7.0f;

  // ---- scatter per-axis sample weights into WY / WX ----
  if (t < 2 * PP * SR) {
    const int  isX = (t >= PP * SR) ? 1 : 0;
    const int  i   = t - isX * PP * SR;                       // 0..13
    const float off = (float)(i >> 1) + ((float)(i & 1) + 0.5f) * 0.5f;
    const float base = isX ? x1 : y1;
    const float sc   = isX ? sx : sy;
    const float pos  = __fadd_rn(base, __fmul_rn(off, sc));
    if (pos > -1.0f && pos < 128.0f) {
      const float pc = fminf(fmaxf(pos, 0.0f), 127.0f);
      const int   p0 = (int)floorf(pc);
      const int   p1 = min(p0 + 1, 127);
      const float l  = pc - (float)p0;
      float* Warr = isX ? WX : WY;
      atomicAdd(&Warr[p0], 1.0f - l);
      atomicAdd(&Warr[p1], l);
    }
  }
  __syncthreads();

  // ---- compact nonzero rows; find col span (two threads, different waves) ----
  if (t == 0) {
    int n = 0;
    for (int y = 0; y < HH; ++y)
      if (WY[y] != 0.f) { rowIdx[n] = y; rowW[n] = WY[y]; ++n; }
    nrowsS = n;
  }
  if (t == 64) {
    int lo = 0, hi = -1;
    for (int x = 0; x < WW; ++x)       if (WX[x] != 0.f) hi = x;
    for (int x = WW - 1; x >= 0; --x)  if (WX[x] != 0.f) lo = x;
    xloS = lo & ~3;   // align for float4
    xhiS = hi;        // hi = -1 -> empty loop
  }
  __syncthreads();

  const int nrows = nrowsS;
  const int xlo = xloS, xhi = xhiS;

  // ---- main gather: thread t owns channel t ----
  const float* fb = fm + ((size_t)b * CC + t) * (size_t)(HH * WW);
  float acc = 0.f;
  for (int r = 0; r < nrows; ++r) {
    const float* rowp = fb + rowIdx[r] * WW;
    float rs = 0.f;
    for (int x = xlo; x <= xhi; x += 4) {
      const float4 v = *(const float4*)(rowp + x);
      rs += WX[x] * v.x + WX[x + 1] * v.y + WX[x + 2] * v.z + WX[x + 3] * v.w;
    }
    acc += rowW[r] * rs;
  }
  out[(size_t)roi * CC + t] = acc * (1.0f / 196.0f);

  // ---- gt output ----
  if (t == 0) out[(size_t)N * CC + roi] = rois[roi * 6 + 1];
}

extern "C" void kernel_launch(void* const* d_in, const int* in_sizes, int n_in,
                              void* d_out, int out_size, void* d_ws, size_t ws_size,
                              hipStream_t stream) {
  const float* fm   = (const float*)d_in[0];
  const float* rois = (const float*)d_in[1];
  float* out = (float*)d_out;
  const int N = in_sizes[1] / 6;
  roi_pool_kernel<<<N, 256, 0, stream>>>(fm, rois, out, N);
}

// Round 2
// 84.518 us; speedup vs baseline: 1.8604x; 1.8604x over previous
//
#include <hip/hip_runtime.h>
#include <hip/hip_fp16.h>

#define PP 7
#define SR 2
#define HH 128
#define WW 128
#define CC 256
#define CHUNKS 4        // blocks per ROI
#define CH_PER_WAVE 16  // 256 channels / (4 chunks * 4 waves)

__global__ __launch_bounds__(256) void roi_pool_kernel(
    const float* __restrict__ fm, const float* __restrict__ rois,
    float* __restrict__ out, int N) {
  // XCD-aware bijective swizzle (grid = N*CHUNKS, divisible by 8 for N=512)
  const int nwg = gridDim.x;
  const int bid = blockIdx.x;
  const int lb = ((nwg & 7) == 0) ? ((bid & 7) * (nwg >> 3) + (bid >> 3)) : bid;
  const int roi = lb / CHUNKS;
  const int chunk = lb % CHUNKS;
  const int t = threadIdx.x;
  const int wave = t >> 6;
  const int lane = t & 63;

  __shared__ float WX[WW], WY[HH];
  __shared__ int rowIdx[32];
  __shared__ float rowW[32];
  __shared__ int nrowsS, xloS, xhiS;

  if (t < 128) { WX[t] = 0.f; WY[t] = 0.f; }
  __syncthreads();

  // ---- geometry (redundant per-thread, cheap) ----
  const float bf  = rois[roi * 6 + 0];
  const float cx  = rois[roi * 6 + 2];
  const float cy  = rois[roi * 6 + 3];
  const float w_  = rois[roi * 6 + 4];
  const float h_  = rois[roi * 6 + 5];

  // f16 round-trip, contraction-free (match jnp float16 cast semantics)
  const float x1 = __half2float(__float2half(
      __fmul_rn(__fsub_rn(cx, __fmul_rn(0.5f, w_)), (float)HH)));
  const float y1 = __half2float(__float2half(
      __fmul_rn(__fsub_rn(cy, __fmul_rn(0.5f, h_)), (float)WW)));
  const float x2 = __half2float(__float2half(
      __fmul_rn(__fadd_rn(cx, __fmul_rn(0.5f, w_)), (float)HH)));
  const float y2 = __half2float(__float2half(
      __fadd_rn(cy, __fmul_rn(0.5f, h_)) * (float)WW));

  const float roi_w = fmaxf(__fsub_rn(x2, x1), 1.0f);
  const float roi_h = fmaxf(__fsub_rn(y2, y1), 1.0f);
  const float sx = roi_w / 7.0f;
  const float sy = roi_h / 7.0f;

  // ---- scatter per-axis sample weights into WY / WX ----
  if (t < 2 * PP * SR) {
    const int  isX = (t >= PP * SR) ? 1 : 0;
    const int  i   = t - isX * PP * SR;                      // 0..13
    const float off = (float)(i >> 1) + ((float)(i & 1) + 0.5f) * 0.5f;
    const float base = isX ? x1 : y1;
    const float sc   = isX ? sx : sy;
    const float pos  = __fadd_rn(base, __fmul_rn(off, sc));
    if (pos > -1.0f && pos < 128.0f) {
      const float pc = fminf(fmaxf(pos, 0.0f), 127.0f);
      const int   p0 = (int)floorf(pc);
      const int   p1 = min(p0 + 1, 127);
      const float l  = pc - (float)p0;
      float* Warr = isX ? WX : WY;
      atomicAdd(&Warr[p0], 1.0f - l);
      atomicAdd(&Warr[p1], l);
    }
  }
  __syncthreads();

  // ---- compact nonzero rows; find col span (two threads, different waves) ----
  if (t == 0) {
    int n = 0;
    for (int y = 0; y < HH; ++y)
      if (WY[y] != 0.f) { rowIdx[n] = y; rowW[n] = WY[y]; ++n; }
    nrowsS = n;
  }
  if (t == 64) {
    int lo = 0, hi = -1;
    for (int x = 0; x < WW; ++x)       if (WX[x] != 0.f) hi = x;
    for (int x = WW - 1; x >= 0; --x)  if (WX[x] != 0.f) lo = x;
    xloS = lo;
    xhiS = hi;       // hi = -1 -> empty
  }
  __syncthreads();

  const int nrows = nrowsS;
  const int xlo = xloS;
  const int span = xhiS - xlo;                 // < 64 always; may be negative

  const int b = __builtin_amdgcn_readfirstlane((int)bf);
  const int cbase = chunk * 64 + wave * CH_PER_WAVE;

  float acc[CH_PER_WAVE];
  #pragma unroll
  for (int c = 0; c < CH_PER_WAVE; ++c) acc[c] = 0.f;

  if (span >= 0 && nrows > 0) {
    const int   xl = xlo + min(lane, span);    // idle lanes dup xlo (free)
    const float wx = (lane <= span) ? WX[xl] : 0.f;
    const float* base0 = fm + ((size_t)b * CC + cbase) * (size_t)(HH * WW) + xl;
    for (int r = 0; r < nrows; ++r) {
      const float wr = rowW[r] * wx;
      const float* p = base0 + rowIdx[r] * WW;
      #pragma unroll
      for (int c = 0; c < CH_PER_WAVE; ++c)
        acc[c] += wr * p[c * (HH * WW)];
    }
  }

  // ---- per-channel wave reduction, lane 0 writes ----
  #pragma unroll
  for (int c = 0; c < CH_PER_WAVE; ++c) {
    float v = acc[c];
    #pragma unroll
    for (int m = 32; m >= 1; m >>= 1) v += __shfl_xor(v, m, 64);
    if (lane == 0) out[(size_t)roi * CC + cbase + c] = v * (1.0f / 196.0f);
  }

  // ---- gt output ----
  if (chunk == 0 && t == 0) out[(size_t)N * CC + roi] = rois[roi * 6 + 1];
}

extern "C" void kernel_launch(void* const* d_in, const int* in_sizes, int n_in,
                              void* d_out, int out_size, void* d_ws, size_t ws_size,
                              hipStream_t stream) {
  const float* fm   = (const float*)d_in[0];
  const float* rois = (const float*)d_in[1];
  float* out = (float*)d_out;
  const int N = in_sizes[1] / 6;
  roi_pool_kernel<<<N * CHUNKS, 256, 0, stream>>>(fm, rois, out, N);
}

// Round 3
// 76.813 us; speedup vs baseline: 2.0470x; 1.1003x over previous
//
#include <hip/hip_runtime.h>
#include <hip/hip_fp16.h>

#define PP 7
#define SR 2
#define HH 128
#define WW 128
#define CC 256
#define PLANE (HH * WW)
#define NCHUNK 16   // channel chunks per ROI (one wave each)
#define CPW 16      // channels per wave

__global__ __launch_bounds__(64) void roi_pool_kernel(
    const float* __restrict__ fm, const float* __restrict__ rois,
    float* __restrict__ out, int N) {
  const int nwg = gridDim.x;
  const int bid = blockIdx.x;
  // bijective XCD swizzle (grid divisible by 8 for N=512)
  const int lb = ((nwg & 7) == 0) ? ((bid & 7) * (nwg >> 3) + (bid >> 3)) : bid;
  const int roi = lb / NCHUNK;
  const int chunk = lb % NCHUNK;
  const int lane = threadIdx.x;

  __shared__ float WX[WW], WY[HH];
  __shared__ int rowIdx[32];
  __shared__ float rowW[32];

  WX[lane] = 0.f; WX[lane + 64] = 0.f;
  WY[lane] = 0.f; WY[lane + 64] = 0.f;
  __syncthreads();

  // ---- geometry (redundant per-lane) ----
  const float bf = rois[roi * 6 + 0];
  const float cx = rois[roi * 6 + 2];
  const float cy = rois[roi * 6 + 3];
  const float w_ = rois[roi * 6 + 4];
  const float h_ = rois[roi * 6 + 5];

  // f16 round-trip, contraction-free (match jnp float16 cast semantics)
  const float x1 = __half2float(__float2half(
      __fmul_rn(__fsub_rn(cx, __fmul_rn(0.5f, w_)), 128.0f)));
  const float y1 = __half2float(__float2half(
      __fmul_rn(__fsub_rn(cy, __fmul_rn(0.5f, h_)), 128.0f)));
  const float x2 = __half2float(__float2half(
      __fmul_rn(__fadd_rn(cx, __fmul_rn(0.5f, w_)), 128.0f)));
  const float y2 = __half2float(__float2half(
      __fmul_rn(__fadd_rn(cy, __fmul_rn(0.5f, h_)), 128.0f)));

  const float sx = fmaxf(__fsub_rn(x2, x1), 1.0f) / 7.0f;
  const float sy = fmaxf(__fsub_rn(y2, y1), 1.0f) / 7.0f;

  // ---- scatter per-axis sample weights ----
  if (lane < 2 * PP * SR) {
    const int isX = lane >= PP * SR;
    const int i = lane - isX * PP * SR;          // 0..13
    const float off = (float)(i >> 1) + ((float)(i & 1) + 0.5f) * 0.5f;
    const float pos = __fadd_rn(isX ? x1 : y1, __fmul_rn(off, isX ? sx : sy));
    if (pos > -1.0f && pos < 128.0f) {
      const float pc = fminf(fmaxf(pos, 0.0f), 127.0f);
      const int p0 = (int)floorf(pc);
      const int p1 = min(p0 + 1, 127);
      const float l = pc - (float)p0;
      float* Warr = isX ? WX : WY;
      atomicAdd(&Warr[p0], 1.0f - l);
      atomicAdd(&Warr[p1], l);
    }
  }
  __syncthreads();

  // ---- wave-parallel compaction of nonzero rows + x span ----
  const float wy0 = WY[lane], wy1 = WY[lane + 64];
  const unsigned long long by0 = __ballot(wy0 != 0.f);
  const unsigned long long by1 = __ballot(wy1 != 0.f);
  const unsigned long long below = (lane == 0) ? 0ull : (~0ull >> (64 - lane));
  const int n0 = __popcll(by0);
  if (wy0 != 0.f) { const int p = __popcll(by0 & below); rowIdx[p] = lane; rowW[p] = wy0; }
  if (wy1 != 0.f) { const int p = n0 + __popcll(by1 & below); rowIdx[p] = lane + 64; rowW[p] = wy1; }
  const int nrows = n0 + __popcll(by1);

  const float wxa = WX[lane], wxb = WX[lane + 64];
  const unsigned long long bx0 = __ballot(wxa != 0.f);
  const unsigned long long bx1 = __ballot(wxb != 0.f);
  const int xlo = bx0 ? __builtin_ctzll(bx0) : (bx1 ? 64 + __builtin_ctzll(bx1) : 0);
  const int xhi = bx1 ? 64 + (63 - __builtin_clzll(bx1))
                      : (bx0 ? (63 - __builtin_clzll(bx0)) : -1);
  __syncthreads();

  // ---- main gather: 2-D lane layout (rowstep rows) x (nx4 float4 cols) ----
  float acc[CPW];
  #pragma unroll
  for (int c = 0; c < CPW; ++c) acc[c] = 0.f;

  if (nrows > 0 && xhi >= 0) {
    const int b = (int)bf;
    const int x4lo = xlo >> 2;
    const int x4cnt = (xhi >> 2) - x4lo + 1;            // <= 15
    const int l2 = (x4cnt <= 1) ? 0 : (32 - __clz(x4cnt - 1));  // ceil log2
    const int nx4 = 1 << l2;
    const int rowstep = 64 >> l2;
    const int xi = lane & (nx4 - 1);
    const int ri = lane >> l2;
    const bool xv = xi < x4cnt;
    const int col4 = xv ? (x4lo + xi) : x4lo;           // dup lanes share line
    float4 wx4 = make_float4(0.f, 0.f, 0.f, 0.f);
    if (xv) wx4 = *(const float4*)&WX[col4 << 2];
    const float* cb = fm + ((size_t)b * CC + chunk * CPW) * PLANE + (col4 << 2);

    for (int r0 = 0; r0 < nrows; r0 += rowstep) {
      const int rI = r0 + ri;
      const bool rv = rI < nrows;
      const int row = rowIdx[rv ? rI : 0];
      const float wy = rv ? rowW[rI] : 0.f;
      const float w0 = wx4.x * wy, w1 = wx4.y * wy;
      const float w2 = wx4.z * wy, w3 = wx4.w * wy;
      const float* p = cb + row * WW;
      #pragma unroll
      for (int c = 0; c < CPW; ++c) {
        const float4 v = *(const float4*)(p + c * PLANE);
        acc[c] = fmaf(w0, v.x, acc[c]);
        acc[c] = fmaf(w1, v.y, acc[c]);
        acc[c] = fmaf(w2, v.z, acc[c]);
        acc[c] = fmaf(w3, v.w, acc[c]);
      }
    }
  }

  // ---- 64-lane reduce per channel, lane c writes channel c ----
  const size_t obase = (size_t)roi * CC + chunk * CPW;
  #pragma unroll
  for (int c = 0; c < CPW; ++c) {
    float v = acc[c];
    #pragma unroll
    for (int m = 32; m >= 1; m >>= 1) v += __shfl_xor(v, m, 64);
    if (lane == c) out[obase + c] = v * (1.0f / 196.0f);
  }

  // ---- gt output ----
  if (chunk == 0 && lane == 0) out[(size_t)N * CC + roi] = rois[roi * 6 + 1];
}

extern "C" void kernel_launch(void* const* d_in, const int* in_sizes, int n_in,
                              void* d_out, int out_size, void* d_ws, size_t ws_size,
                              hipStream_t stream) {
  const float* fm   = (const float*)d_in[0];
  const float* rois = (const float*)d_in[1];
  float* out = (float*)d_out;
  const int N = in_sizes[1] / 6;
  roi_pool_kernel<<<N * NCHUNK, 64, 0, stream>>>(fm, rois, out, N);
}

// Round 4
// 50.348 us; speedup vs baseline: 3.1231x; 1.5256x over previous
//
#include <hip/hip_runtime.h>
#include <hip/hip_fp16.h>

#define PP 7
#define SR 2
#define HH 128
#define WW 128
#define CC 256
#define PLANE (HH * WW)
#define CPW 16   // channels per wave; block = 4 waves = 64-channel quad

__global__ __launch_bounds__(256, 8) void roi_pool_kernel(
    const float* __restrict__ fm, const float* __restrict__ rois,
    float* __restrict__ out, int N) {
  const int nwg = gridDim.x;          // N * 4
  const int bid = blockIdx.x;
  // XCD-sliced mapping: XCD x = bid&7 owns channel-quad x>>1 and ROI-half x&1,
  // iterating ROIs in order -> per-XCD working set ~= 64ch x 1 image ~= 4MB (one L2)
  int roi, quad;
  if ((nwg & 7) == 0) {
    const int x = bid & 7, j = bid >> 3;
    quad = x >> 1;
    roi = (x & 1) * (nwg >> 3) + j;
  } else {
    roi = bid >> 2;
    quad = bid & 3;
  }
  const int t = threadIdx.x;
  const int wave = t >> 6;
  const int lane = t & 63;

  __shared__ float WX[WW], WY[HH];
  __shared__ int rowIdx[32];
  __shared__ float rowW[32];

  if (t < 128) { WX[t] = 0.f; WY[t] = 0.f; }
  __syncthreads();

  // ---- geometry (redundant per-thread) ----
  const float bf = rois[roi * 6 + 0];
  const float cx = rois[roi * 6 + 2];
  const float cy = rois[roi * 6 + 3];
  const float w_ = rois[roi * 6 + 4];
  const float h_ = rois[roi * 6 + 5];

  // f16 round-trip, contraction-free (match jnp float16 cast semantics)
  const float x1 = __half2float(__float2half(
      __fmul_rn(__fsub_rn(cx, __fmul_rn(0.5f, w_)), 128.0f)));
  const float y1 = __half2float(__float2half(
      __fmul_rn(__fsub_rn(cy, __fmul_rn(0.5f, h_)), 128.0f)));
  const float x2 = __half2float(__float2half(
      __fmul_rn(__fadd_rn(cx, __fmul_rn(0.5f, w_)), 128.0f)));
  const float y2 = __half2float(__float2half(
      __fmul_rn(__fadd_rn(cy, __fmul_rn(0.5f, h_)), 128.0f)));

  const float sx = fmaxf(__fsub_rn(x2, x1), 1.0f) / 7.0f;
  const float sy = fmaxf(__fsub_rn(y2, y1), 1.0f) / 7.0f;

  // ---- scatter per-axis sample weights (threads 0..27, all in wave 0) ----
  if (t < 2 * PP * SR) {
    const int isX = t >= PP * SR;
    const int i = t - isX * PP * SR;             // 0..13
    const float off = (float)(i >> 1) + ((float)(i & 1) + 0.5f) * 0.5f;
    const float pos = __fadd_rn(isX ? x1 : y1, __fmul_rn(off, isX ? sx : sy));
    if (pos > -1.0f && pos < 128.0f) {
      const float pc = fminf(fmaxf(pos, 0.0f), 127.0f);
      const int p0 = (int)floorf(pc);
      const int p1 = min(p0 + 1, 127);
      const float l = pc - (float)p0;
      float* Warr = isX ? WX : WY;
      atomicAdd(&Warr[p0], 1.0f - l);
      atomicAdd(&Warr[p1], l);
    }
  }
  __syncthreads();

  // ---- per-wave ballot compaction (identical results in every wave) ----
  const float wy0 = WY[lane], wy1 = WY[lane + 64];
  const unsigned long long by0 = __ballot(wy0 != 0.f);
  const unsigned long long by1 = __ballot(wy1 != 0.f);
  const unsigned long long below = (lane == 0) ? 0ull : (~0ull >> (64 - lane));
  const int n0 = __popcll(by0);
  if (wave == 0) {
    if (wy0 != 0.f) { const int p = __popcll(by0 & below); rowIdx[p] = lane; rowW[p] = wy0; }
    if (wy1 != 0.f) { const int p = n0 + __popcll(by1 & below); rowIdx[p] = lane + 64; rowW[p] = wy1; }
  }
  const int nrows = n0 + __popcll(by1);

  const float wxa = WX[lane], wxb = WX[lane + 64];
  const unsigned long long bx0 = __ballot(wxa != 0.f);
  const unsigned long long bx1 = __ballot(wxb != 0.f);
  const int xlo = bx0 ? __builtin_ctzll(bx0) : (bx1 ? 64 + __builtin_ctzll(bx1) : 0);
  const int xhi = bx1 ? 64 + (63 - __builtin_clzll(bx1))
                      : (bx0 ? (63 - __builtin_clzll(bx0)) : -1);
  __syncthreads();

  // ---- main gather: (rowstep rows) x (nx4 float4 cols) lane layout ----
  float acc[CPW];
  #pragma unroll
  for (int c = 0; c < CPW; ++c) acc[c] = 0.f;

  const int c0 = quad * 64 + wave * CPW;

  if (nrows > 0 && xhi >= 0) {
    const int b = (int)bf;
    const int x4lo = xlo >> 2;
    const int x4cnt = (xhi >> 2) - x4lo + 1;                    // <= 15
    const int l2 = (x4cnt <= 1) ? 0 : (32 - __clz(x4cnt - 1));  // ceil log2
    const int nx4 = 1 << l2;
    const int rowstep = 64 >> l2;
    const int xi = lane & (nx4 - 1);
    const int ri = lane >> l2;
    const bool xv = xi < x4cnt;
    const int col4 = xv ? (x4lo + xi) : x4lo;                   // dup lanes share line
    float4 wx4 = make_float4(0.f, 0.f, 0.f, 0.f);
    if (xv) wx4 = *(const float4*)&WX[col4 << 2];
    const float* cb = fm + ((size_t)b * CC + c0) * PLANE + (col4 << 2);

    for (int r0 = 0; r0 < nrows; r0 += rowstep) {
      const int rI = r0 + ri;
      const bool rv = rI < nrows;
      const int row = rowIdx[rv ? rI : 0];
      const float wy = rv ? rowW[rI] : 0.f;
      const float w0 = wx4.x * wy, w1 = wx4.y * wy;
      const float w2 = wx4.z * wy, w3 = wx4.w * wy;
      const float* p = cb + row * WW;
      #pragma unroll
      for (int c = 0; c < CPW; ++c) {
        const float4 v = *(const float4*)(p + c * PLANE);
        acc[c] = fmaf(w0, v.x, acc[c]);
        acc[c] = fmaf(w1, v.y, acc[c]);
        acc[c] = fmaf(w2, v.z, acc[c]);
        acc[c] = fmaf(w3, v.w, acc[c]);
      }
    }
  }

  // ---- 64-lane reduce per channel, lane c writes channel c ----
  const size_t obase = (size_t)roi * CC + c0;
  #pragma unroll
  for (int c = 0; c < CPW; ++c) {
    float v = acc[c];
    #pragma unroll
    for (int m = 32; m >= 1; m >>= 1) v += __shfl_xor(v, m, 64);
    if (lane == c) out[obase + c] = v * (1.0f / 196.0f);
  }

  // ---- gt output ----
  if (quad == 0 && t == 0) out[(size_t)N * CC + roi] = rois[roi * 6 + 1];
}

extern "C" void kernel_launch(void* const* d_in, const int* in_sizes, int n_in,
                              void* d_out, int out_size, void* d_ws, size_t ws_size,
                              hipStream_t stream) {
  const float* fm   = (const float*)d_in[0];
  const float* rois = (const float*)d_in[1];
  float* out = (float*)d_out;
  const int N = in_sizes[1] / 6;
  roi_pool_kernel<<<N * 4, 256, 0, stream>>>(fm, rois, out, N);
}

// Round 5
// 46.678 us; speedup vs baseline: 3.3686x; 1.0786x over previous
//
#include <hip/hip_runtime.h>
#include <hip/hip_fp16.h>

#define PP 7
#define SR 2
#define HH 128
#define WW 128
#define CC 256
#define PLANE (HH * WW)
#define CPW 16   // channels per wave; block = 4 waves = 64-channel quad

// (256,4): 128-VGPR budget so the 16 channel loads + 16 accs stay in registers
// with full memory-level parallelism. (256,8) forced VGPR=24 -> MLP ~2 (R4).
__global__ __launch_bounds__(256, 4) void roi_pool_kernel(
    const float* __restrict__ fm, const float* __restrict__ rois,
    float* __restrict__ out, int N) {
  const int nwg = gridDim.x;          // N * 4
  const int bid = blockIdx.x;
  // XCD-sliced mapping: XCD x = bid&7 owns channel-quad x>>1 and ROI-half x&1,
  // iterating ROIs in order -> per-XCD working set ~= 64ch x 1 image ~= 4MB (one L2)
  int roi, quad;
  if ((nwg & 7) == 0) {
    const int x = bid & 7, j = bid >> 3;
    quad = x >> 1;
    roi = (x & 1) * (nwg >> 3) + j;
  } else {
    roi = bid >> 2;
    quad = bid & 3;
  }
  const int t = threadIdx.x;
  const int wave = t >> 6;
  const int lane = t & 63;

  __shared__ float WX[WW], WY[HH];
  __shared__ int rowIdx[32];
  __shared__ float rowW[32];

  if (t < 128) { WX[t] = 0.f; WY[t] = 0.f; }
  __syncthreads();

  // ---- geometry (redundant per-thread) ----
  const float bf = rois[roi * 6 + 0];
  const float cx = rois[roi * 6 + 2];
  const float cy = rois[roi * 6 + 3];
  const float w_ = rois[roi * 6 + 4];
  const float h_ = rois[roi * 6 + 5];

  // f16 round-trip, contraction-free (match jnp float16 cast semantics)
  const float x1 = __half2float(__float2half(
      __fmul_rn(__fsub_rn(cx, __fmul_rn(0.5f, w_)), 128.0f)));
  const float y1 = __half2float(__float2half(
      __fmul_rn(__fsub_rn(cy, __fmul_rn(0.5f, h_)), 128.0f)));
  const float x2 = __half2float(__float2half(
      __fmul_rn(__fadd_rn(cx, __fmul_rn(0.5f, w_)), 128.0f)));
  const float y2 = __half2float(__float2half(
      __fmul_rn(__fadd_rn(cy, __fmul_rn(0.5f, h_)), 128.0f)));

  const float sx = fmaxf(__fsub_rn(x2, x1), 1.0f) / 7.0f;
  const float sy = fmaxf(__fsub_rn(y2, y1), 1.0f) / 7.0f;

  // ---- scatter per-axis sample weights (threads 0..27, all in wave 0) ----
  if (t < 2 * PP * SR) {
    const int isX = t >= PP * SR;
    const int i = t - isX * PP * SR;             // 0..13
    const float off = (float)(i >> 1) + ((float)(i & 1) + 0.5f) * 0.5f;
    const float pos = __fadd_rn(isX ? x1 : y1, __fmul_rn(off, isX ? sx : sy));
    if (pos > -1.0f && pos < 128.0f) {
      const float pc = fminf(fmaxf(pos, 0.0f), 127.0f);
      const int p0 = (int)floorf(pc);
      const int p1 = min(p0 + 1, 127);
      const float l = pc - (float)p0;
      float* Warr = isX ? WX : WY;
      atomicAdd(&Warr[p0], 1.0f - l);
      atomicAdd(&Warr[p1], l);
    }
  }
  __syncthreads();

  // ---- per-wave ballot compaction (identical results in every wave) ----
  const float wy0 = WY[lane], wy1 = WY[lane + 64];
  const unsigned long long by0 = __ballot(wy0 != 0.f);
  const unsigned long long by1 = __ballot(wy1 != 0.f);
  const unsigned long long below = (lane == 0) ? 0ull : (~0ull >> (64 - lane));
  const int n0 = __popcll(by0);
  if (wave == 0) {
    if (wy0 != 0.f) { const int p = __popcll(by0 & below); rowIdx[p] = lane; rowW[p] = wy0; }
    if (wy1 != 0.f) { const int p = n0 + __popcll(by1 & below); rowIdx[p] = lane + 64; rowW[p] = wy1; }
  }
  const int nrows = n0 + __popcll(by1);

  const float wxa = WX[lane], wxb = WX[lane + 64];
  const unsigned long long bx0 = __ballot(wxa != 0.f);
  const unsigned long long bx1 = __ballot(wxb != 0.f);
  const int xlo = bx0 ? __builtin_ctzll(bx0) : (bx1 ? 64 + __builtin_ctzll(bx1) : 0);
  const int xhi = bx1 ? 64 + (63 - __builtin_clzll(bx1))
                      : (bx0 ? (63 - __builtin_clzll(bx0)) : -1);
  __syncthreads();

  // ---- main gather: (rowstep rows) x (nx4 float4 cols) lane layout ----
  float acc[CPW];
  #pragma unroll
  for (int c = 0; c < CPW; ++c) acc[c] = 0.f;

  const int c0 = quad * 64 + wave * CPW;

  if (nrows > 0 && xhi >= 0) {
    const int b = (int)bf;
    const int x4lo = xlo >> 2;
    const int x4cnt = (xhi >> 2) - x4lo + 1;                    // <= 15
    const int l2 = (x4cnt <= 1) ? 0 : (32 - __clz(x4cnt - 1));  // ceil log2
    const int nx4 = 1 << l2;
    const int rowstep = 64 >> l2;
    const int xi = lane & (nx4 - 1);
    const int ri = lane >> l2;
    const bool xv = xi < x4cnt;
    const int col4 = xv ? (x4lo + xi) : x4lo;                   // dup lanes share line
    float4 wx4 = make_float4(0.f, 0.f, 0.f, 0.f);
    if (xv) wx4 = *(const float4*)&WX[col4 << 2];
    const float* cb = fm + ((size_t)b * CC + c0) * PLANE + (col4 << 2);

    for (int r0 = 0; r0 < nrows; r0 += rowstep) {
      const int rI = r0 + ri;
      const bool rv = rI < nrows;
      const int row = rowIdx[rv ? rI : 0];
      const float wy = rv ? rowW[rI] : 0.f;
      const float w0 = wx4.x * wy, w1 = wx4.y * wy;
      const float w2 = wx4.z * wy, w3 = wx4.w * wy;
      const float* p = cb + row * WW;

      // load all 16 channels first (16 dwordx4 in flight), then FMA
      float4 v[CPW];
      #pragma unroll
      for (int c = 0; c < CPW; ++c) v[c] = *(const float4*)(p + c * PLANE);
      #pragma unroll
      for (int c = 0; c < CPW; ++c) {
        acc[c] = fmaf(w0, v[c].x, acc[c]);
        acc[c] = fmaf(w1, v[c].y, acc[c]);
        acc[c] = fmaf(w2, v[c].z, acc[c]);
        acc[c] = fmaf(w3, v[c].w, acc[c]);
      }
    }
  }

  // ---- 64-lane reduce per channel, lane c writes channel c ----
  const size_t obase = (size_t)roi * CC + c0;
  #pragma unroll
  for (int c = 0; c < CPW; ++c) {
    float v = acc[c];
    #pragma unroll
    for (int m = 32; m >= 1; m >>= 1) v += __shfl_xor(v, m, 64);
    if (lane == c) out[obase + c] = v * (1.0f / 196.0f);
  }

  // ---- gt output ----
  if (quad == 0 && t == 0) out[(size_t)N * CC + roi] = rois[roi * 6 + 1];
}

extern "C" void kernel_launch(void* const* d_in, const int* in_sizes, int n_in,
                              void* d_out, int out_size, void* d_ws, size_t ws_size,
                              hipStream_t stream) {
  const float* fm   = (const float*)d_in[0];
  const float* rois = (const float*)d_in[1];
  float* out = (float*)d_out;
  const int N = in_sizes[1] / 6;
  roi_pool_kernel<<<N * 4, 256, 0, stream>>>(fm, rois, out, N);
}

// Round 6
// 45.554 us; speedup vs baseline: 3.4517x; 1.0247x over previous
//
#include <hip/hip_runtime.h>
#include <hip/hip_fp16.h>

#define PP 7
#define SR 2
#define HH 128
#define WW 128
#define CC 256
#define PLANE (HH * WW)
#define CPW 16   // channels per wave; block = 4 waves = 64-channel quad

// (256,4): 128-VGPR budget so the 16 channel loads + 16 accs stay in registers
// with full memory-level parallelism. (256,8) forced VGPR=24 -> MLP ~2 (R4).
__global__ __launch_bounds__(256, 4) void roi_pool_kernel(
    const float* __restrict__ fm, const float* __restrict__ rois,
    float* __restrict__ out, int N) {
  const int nwg = gridDim.x;          // N * 4
  const int bid = blockIdx.x;
  // XCD-sliced mapping: XCD x = bid&7 owns channel-quad x>>1 and ROI-half x&1,
  // iterating ROIs in order -> per-XCD working set ~= 64ch x 1 image ~= 4MB (one L2)
  int roi, quad;
  if ((nwg & 7) == 0) {
    const int x = bid & 7, j = bid >> 3;
    quad = x >> 1;
    roi = (x & 1) * (nwg >> 3) + j;
  } else {
    roi = bid >> 2;
    quad = bid & 3;
  }
  const int t = threadIdx.x;
  const int wave = t >> 6;
  const int lane = t & 63;

  __shared__ float WX[WW], WY[HH];
  __shared__ int rowIdx[32];
  __shared__ float rowW[32];

  if (t < 128) { WX[t] = 0.f; WY[t] = 0.f; }
  __syncthreads();

  // ---- geometry (redundant per-thread) ----
  const float bf = rois[roi * 6 + 0];
  const float cx = rois[roi * 6 + 2];
  const float cy = rois[roi * 6 + 3];
  const float w_ = rois[roi * 6 + 4];
  const float h_ = rois[roi * 6 + 5];

  // f16 round-trip, contraction-free (match jnp float16 cast semantics)
  const float x1 = __half2float(__float2half(
      __fmul_rn(__fsub_rn(cx, __fmul_rn(0.5f, w_)), 128.0f)));
  const float y1 = __half2float(__float2half(
      __fmul_rn(__fsub_rn(cy, __fmul_rn(0.5f, h_)), 128.0f)));
  const float x2 = __half2float(__float2half(
      __fmul_rn(__fadd_rn(cx, __fmul_rn(0.5f, w_)), 128.0f)));
  const float y2 = __half2float(__float2half(
      __fmul_rn(__fadd_rn(cy, __fmul_rn(0.5f, h_)), 128.0f)));

  const float sx = fmaxf(__fsub_rn(x2, x1), 1.0f) / 7.0f;
  const float sy = fmaxf(__fsub_rn(y2, y1), 1.0f) / 7.0f;

  // ---- scatter per-axis sample weights (threads 0..27, all in wave 0) ----
  if (t < 2 * PP * SR) {
    const int isX = t >= PP * SR;
    const int i = t - isX * PP * SR;             // 0..13
    const float off = (float)(i >> 1) + ((float)(i & 1) + 0.5f) * 0.5f;
    const float pos = __fadd_rn(isX ? x1 : y1, __fmul_rn(off, isX ? sx : sy));
    if (pos > -1.0f && pos < 128.0f) {
      const float pc = fminf(fmaxf(pos, 0.0f), 127.0f);
      const int p0 = (int)floorf(pc);
      const int p1 = min(p0 + 1, 127);
      const float l = pc - (float)p0;
      float* Warr = isX ? WX : WY;
      atomicAdd(&Warr[p0], 1.0f - l);
      atomicAdd(&Warr[p1], l);
    }
  }
  __syncthreads();

  // ---- per-wave ballot compaction (identical results in every wave) ----
  const float wy0 = WY[lane], wy1 = WY[lane + 64];
  const unsigned long long by0 = __ballot(wy0 != 0.f);
  const unsigned long long by1 = __ballot(wy1 != 0.f);
  const unsigned long long below = (lane == 0) ? 0ull : (~0ull >> (64 - lane));
  const int n0 = __popcll(by0);
  if (wave == 0) {
    if (wy0 != 0.f) { const int p = __popcll(by0 & below); rowIdx[p] = lane; rowW[p] = wy0; }
    if (wy1 != 0.f) { const int p = n0 + __popcll(by1 & below); rowIdx[p] = lane + 64; rowW[p] = wy1; }
  }
  const int nrows = n0 + __popcll(by1);

  const float wxa = WX[lane], wxb = WX[lane + 64];
  const unsigned long long bx0 = __ballot(wxa != 0.f);
  const unsigned long long bx1 = __ballot(wxb != 0.f);
  const int xlo = bx0 ? __builtin_ctzll(bx0) : (bx1 ? 64 + __builtin_ctzll(bx1) : 0);
  const int xhi = bx1 ? 64 + (63 - __builtin_clzll(bx1))
                      : (bx0 ? (63 - __builtin_clzll(bx0)) : -1);
  __syncthreads();

  // ---- main gather: (rowstep rows) x (nx4 float4 cols) lane layout ----
  float acc[CPW];
  #pragma unroll
  for (int c = 0; c < CPW; ++c) acc[c] = 0.f;

  const int c0 = quad * 64 + wave * CPW;

  if (nrows > 0 && xhi >= 0) {
    const int b = (int)bf;
    const int x4lo = xlo >> 2;
    const int x4cnt = (xhi >> 2) - x4lo + 1;                    // <= 15
    const int l2 = (x4cnt <= 1) ? 0 : (32 - __clz(x4cnt - 1));  // ceil log2
    const int nx4 = 1 << l2;
    const int rowstep = 64 >> l2;
    const int xi = lane & (nx4 - 1);
    const int ri = lane >> l2;
    const bool xv = xi < x4cnt;
    const int col4 = xv ? (x4lo + xi) : x4lo;                   // dup lanes share line
    float4 wx4 = make_float4(0.f, 0.f, 0.f, 0.f);
    if (xv) wx4 = *(const float4*)&WX[col4 << 2];
    const float* cb = fm + ((size_t)b * CC + c0) * PLANE + (col4 << 2);

    for (int r0 = 0; r0 < nrows; r0 += rowstep) {
      const int rI = r0 + ri;
      const bool rv = rI < nrows;
      const int row = rowIdx[rv ? rI : 0];
      const float wy = rv ? rowW[rI] : 0.f;
      const float w0 = wx4.x * wy, w1 = wx4.y * wy;
      const float w2 = wx4.z * wy, w3 = wx4.w * wy;
      const float* p = cb + row * WW;

      // Issue ALL 16 channel loads before any FMA. The sched_barrier pins the
      // batch: without it the scheduler sinks each load to its use (MLP ~1,
      // VGPR=36 in R5). Fine-grained vmcnt waits still let FMAs overlap the
      // tail of the load batch.
      float4 v[CPW];
      #pragma unroll
      for (int c = 0; c < CPW; ++c) v[c] = *(const float4*)(p + c * PLANE);
      __builtin_amdgcn_sched_barrier(0);
      #pragma unroll
      for (int c = 0; c < CPW; ++c) {
        acc[c] = fmaf(w0, v[c].x, acc[c]);
        acc[c] = fmaf(w1, v[c].y, acc[c]);
        acc[c] = fmaf(w2, v[c].z, acc[c]);
        acc[c] = fmaf(w3, v[c].w, acc[c]);
      }
    }
  }

  // ---- 64-lane reduce per channel, lane c writes channel c ----
  const size_t obase = (size_t)roi * CC + c0;
  #pragma unroll
  for (int c = 0; c < CPW; ++c) {
    float v = acc[c];
    #pragma unroll
    for (int m = 32; m >= 1; m >>= 1) v += __shfl_xor(v, m, 64);
    if (lane == c) out[obase + c] = v * (1.0f / 196.0f);
  }

  // ---- gt output ----
  if (quad == 0 && t == 0) out[(size_t)N * CC + roi] = rois[roi * 6 + 1];
}

extern "C" void kernel_launch(void* const* d_in, const int* in_sizes, int n_in,
                              void* d_out, int out_size, void* d_ws, size_t ws_size,
                              hipStream_t stream) {
  const float* fm   = (const float*)d_in[0];
  const float* rois = (const float*)d_in[1];
  float* out = (float*)d_out;
  const int N = in_sizes[1] / 6;
  roi_pool_kernel<<<N * 4, 256, 0, stream>>>(fm, rois, out, N);
}

// Round 8
// 41.730 us; speedup vs baseline: 3.7680x; 1.0916x over previous
//
#include <hip/hip_runtime.h>
#include <hip/hip_fp16.h>

#define PP 7
#define SR 2
#define HH 128
#define WW 128
#define CC 256
#define PLANE (HH * WW)
#define CPW 16   // channels per wave; block = 4 waves = 64-channel quad

// Forced-MLP load: flat 64-bit VGPR address form, issued via volatile asm so
// the compiler cannot sink the load to its use. All 16 results stay live until
// the explicit s_waitcnt vmcnt(0) -> 16 loads genuinely outstanding.
__device__ __forceinline__ float4 gld128(const float* addr) {
  float4 r;
  asm volatile("global_load_dwordx4 %0, %1, off"
               : "=v"(r) : "v"(addr) : "memory");
  return r;
}

__global__ __launch_bounds__(256, 4) void roi_pool_kernel(
    const float* __restrict__ fm, const float* __restrict__ rois,
    float* __restrict__ out, int N) {
  const int nwg = gridDim.x;          // N * 4
  const int bid = blockIdx.x;
  // XCD-sliced mapping: XCD x = bid&7 owns channel-quad x>>1 and ROI-half x&1,
  // iterating ROIs in order -> per-XCD working set ~= 64ch x 1 image ~= 4MB (one L2)
  int roi, quad;
  if ((nwg & 7) == 0) {
    const int x = bid & 7, j = bid >> 3;
    quad = x >> 1;
    roi = (x & 1) * (nwg >> 3) + j;
  } else {
    roi = bid >> 2;
    quad = bid & 3;
  }
  const int t = threadIdx.x;
  const int wave = t >> 6;
  const int lane = t & 63;

  __shared__ float WX[WW], WY[HH];
  __shared__ int rowIdx[32];
  __shared__ float rowW[32];

  if (t < 128) { WX[t] = 0.f; WY[t] = 0.f; }
  __syncthreads();

  // ---- geometry (redundant per-thread) ----
  const float bf = rois[roi * 6 + 0];
  const float cx = rois[roi * 6 + 2];
  const float cy = rois[roi * 6 + 3];
  const float w_ = rois[roi * 6 + 4];
  const float h_ = rois[roi * 6 + 5];

  // f16 round-trip, contraction-free (match jnp float16 cast semantics)
  const float x1 = __half2float(__float2half(
      __fmul_rn(__fsub_rn(cx, __fmul_rn(0.5f, w_)), 128.0f)));
  const float y1 = __half2float(__float2half(
      __fmul_rn(__fsub_rn(cy, __fmul_rn(0.5f, h_)), 128.0f)));
  const float x2 = __half2float(__float2half(
      __fmul_rn(__fadd_rn(cx, __fmul_rn(0.5f, w_)), 128.0f)));
  const float y2 = __half2float(__float2half(
      __fmul_rn(__fadd_rn(cy, __fmul_rn(0.5f, h_)), 128.0f)));

  const float sx = fmaxf(__fsub_rn(x2, x1), 1.0f) / 7.0f;
  const float sy = fmaxf(__fsub_rn(y2, y1), 1.0f) / 7.0f;

  // ---- scatter per-axis sample weights (threads 0..27, all in wave 0) ----
  if (t < 2 * PP * SR) {
    const int isX = t >= PP * SR;
    const int i = t - isX * PP * SR;             // 0..13
    const float off = (float)(i >> 1) + ((float)(i & 1) + 0.5f) * 0.5f;
    const float pos = __fadd_rn(isX ? x1 : y1, __fmul_rn(off, isX ? sx : sy));
    if (pos > -1.0f && pos < 128.0f) {
      const float pc = fminf(fmaxf(pos, 0.0f), 127.0f);
      const int p0 = (int)floorf(pc);
      const int p1 = min(p0 + 1, 127);
      const float l = pc - (float)p0;
      float* Warr = isX ? WX : WY;
      atomicAdd(&Warr[p0], 1.0f - l);
      atomicAdd(&Warr[p1], l);
    }
  }
  __syncthreads();

  // ---- per-wave ballot compaction (identical results in every wave) ----
  const float wy0 = WY[lane], wy1 = WY[lane + 64];
  const unsigned long long by0 = __ballot(wy0 != 0.f);
  const unsigned long long by1 = __ballot(wy1 != 0.f);
  const unsigned long long below = (lane == 0) ? 0ull : (~0ull >> (64 - lane));
  const int n0 = __popcll(by0);
  if (wave == 0) {
    if (wy0 != 0.f) { const int p = __popcll(by0 & below); rowIdx[p] = lane; rowW[p] = wy0; }
    if (wy1 != 0.f) { const int p = n0 + __popcll(by1 & below); rowIdx[p] = lane + 64; rowW[p] = wy1; }
  }
  const int nrows = n0 + __popcll(by1);

  const float wxa = WX[lane], wxb = WX[lane + 64];
  const unsigned long long bx0 = __ballot(wxa != 0.f);
  const unsigned long long bx1 = __ballot(wxb != 0.f);
  const int xlo = bx0 ? __builtin_ctzll(bx0) : (bx1 ? 64 + __builtin_ctzll(bx1) : 0);
  const int xhi = bx1 ? 64 + (63 - __builtin_clzll(bx1))
                      : (bx0 ? (63 - __builtin_clzll(bx0)) : -1);
  __syncthreads();

  // ---- main gather: (rowstep rows) x (nx4 float4 cols) lane layout ----
  float acc[CPW];
  #pragma unroll
  for (int c = 0; c < CPW; ++c) acc[c] = 0.f;

  const int c0 = quad * 64 + wave * CPW;

  if (nrows > 0 && xhi >= 0) {          // wave-uniform branch
    const int b = (int)bf;
    const int x4lo = xlo >> 2;
    const int x4cnt = (xhi >> 2) - x4lo + 1;                    // <= 15
    const int l2 = (x4cnt <= 1) ? 0 : (32 - __clz(x4cnt - 1));  // ceil log2
    const int nx4 = 1 << l2;
    const int rowstep = 64 >> l2;
    const int xi = lane & (nx4 - 1);
    const int ri = lane >> l2;
    const bool xv = xi < x4cnt;
    const int col4 = xv ? (x4lo + xi) : x4lo;                   // dup lanes share line
    float4 wx4 = make_float4(0.f, 0.f, 0.f, 0.f);
    if (xv) wx4 = *(const float4*)&WX[col4 << 2];
    const float* cb = fm + ((size_t)b * CC + c0) * PLANE + (col4 << 2);

    for (int r0 = 0; r0 < nrows; r0 += rowstep) {
      const int rI = r0 + ri;
      const bool rv = rI < nrows;
      const int row = rowIdx[rv ? rI : 0];
      const float wy = rv ? rowW[rI] : 0.f;
      const float w0 = wx4.x * wy, w1 = wx4.y * wy;
      const float w2 = wx4.z * wy, w3 = wx4.w * wy;
      const float* p = cb + row * WW;

      float4 v[CPW];
      #pragma unroll
      for (int c = 0; c < CPW; ++c) v[c] = gld128(p + c * PLANE);
      asm volatile("s_waitcnt vmcnt(0)" ::: "memory");
      __builtin_amdgcn_sched_barrier(0);
      #pragma unroll
      for (int c = 0; c < CPW; ++c) {
        acc[c] = fmaf(w0, v[c].x, acc[c]);
        acc[c] = fmaf(w1, v[c].y, acc[c]);
        acc[c] = fmaf(w2, v[c].z, acc[c]);
        acc[c] = fmaf(w3, v[c].w, acc[c]);
      }
    }
  }

  // ---- 64-lane reduce per channel, lane c writes channel c ----
  const size_t obase = (size_t)roi * CC + c0;
  #pragma unroll
  for (int c = 0; c < CPW; ++c) {
    float v = acc[c];
    #pragma unroll
    for (int m = 32; m >= 1; m >>= 1) v += __shfl_xor(v, m, 64);
    if (lane == c) out[obase + c] = v * (1.0f / 196.0f);
  }

  // ---- gt output ----
  if (quad == 0 && t == 0) out[(size_t)N * CC + roi] = rois[roi * 6 + 1];
}

extern "C" void kernel_launch(void* const* d_in, const int* in_sizes, int n_in,
                              void* d_out, int out_size, void* d_ws, size_t ws_size,
                              hipStream_t stream) {
  const float* fm   = (const float*)d_in[0];
  const float* rois = (const float*)d_in[1];
  float* out = (float*)d_out;
  const int N = in_sizes[1] / 6;
  roi_pool_kernel<<<N * 4, 256, 0, stream>>>(fm, rois, out, N);
}